// Round 1
// baseline (110.015 us; speedup 1.0000x reference)
//
#include <hip/hip_runtime.h>

#define NSAMP 8192
#define DPOS  8
#define CIN   64
#define COUT  32
#define NPERM 70
#define SPB   8   // samples per block (4 waves x 2 samples/wave)

// out[s,r,o] = T[s,o] + sum_{i in splits0[r]} d[s,i,o]
//   p[i][g]  = dot(x[s,i,:], w[g,o,:])
//   d[i]     = p[i][0] - p[i][1];  T = sum_i p[i][1]
// This collapses the 70-row gather/pool/matmul into 16 dot products + 70
// masked 4-term sums per (s,o). HBM-write-bound: 73.4 MB out + 16.8 MB in.

extern "C" __global__ __launch_bounds__(256, 4)
void pcs_kernel(const float* __restrict__ x,
                const float* __restrict__ w,
                const int*   __restrict__ splits0,
                float*       __restrict__ out)
{
    // LDS: x tile 16 KB + padded w 17.4 KB + masks
    __shared__ float xs[SPB * DPOS * CIN];   // [8 samples][8 pos][64 c], linear
    __shared__ float ws[2 * COUT * 68];      // [g*32+o][68] rows padded 64->68 floats
    __shared__ int   masks[NPERM];

    const int tid     = threadIdx.x;
    const int wave    = tid >> 6;
    const int lane    = tid & 63;
    const int s_sub   = lane >> 5;
    const int o       = lane & 31;
    const int s_local = wave * 2 + s_sub;
    const int block_s = blockIdx.x * SPB;

    // ---- stage x: 16 KB contiguous in global (8 consecutive samples).
    // Each wave DMAs its own 4 KB (it only reads its own 2 samples later).
    {
        const char* xg = (const char*)(x + (size_t)block_s * (DPOS * CIN));
        #pragma unroll
        for (int k = 0; k < 4; ++k) {
            const int byte_off = wave * 4096 + k * 1024;  // wave-uniform
            __builtin_amdgcn_global_load_lds(
                (const __attribute__((address_space(1))) void*)(xg + byte_off + lane * 16),
                (__attribute__((address_space(3))) void*)((char*)xs + byte_off),
                16, 0, 0);
        }
    }

    // ---- stage w with +4 float row padding (stride 68 => bank pattern 4*o+4*cc,
    // baseline-equivalent for ds_read_b128; unpadded stride 64 would be 32-way).
    {
        #pragma unroll
        for (int q = 0; q < 4; ++q) {
            const int v4 = q * 256 + tid;        // float4 index, coalesced read
            const int f  = v4 * 4;               // flat float index 0..4095
            const float4 val = *(const float4*)(w + f);
            const int row = f >> 6;              // g*32+o
            const int c   = f & 63;
            *(float4*)(ws + row * 68 + c) = val;
        }
    }

    // ---- splits0 rows -> 8-bit position masks
    if (tid < NPERM) {
        const int4 si = *(const int4*)(splits0 + tid * 4);
        masks[tid] = (1 << si.x) | (1 << si.y) | (1 << si.z) | (1 << si.w);
    }

    asm volatile("s_waitcnt vmcnt(0)" ::: "memory"); // drain global_load_lds
    __syncthreads();

    // ---- projection: acc{0,1}[i] = dot(x[s,i,:], w[{0,1},o,:])
    float acc0[DPOS], acc1[DPOS];
    #pragma unroll
    for (int i = 0; i < DPOS; ++i) { acc0[i] = 0.f; acc1[i] = 0.f; }

    const float* xrow = xs + s_local * (DPOS * CIN);  // half-wave-uniform -> LDS broadcast
    const float* w0p  = ws + o * 68;
    const float* w1p  = ws + (COUT + o) * 68;

    #pragma unroll 4
    for (int cc = 0; cc < 16; ++cc) {
        const float4 w0 = *(const float4*)(w0p + cc * 4);
        const float4 w1 = *(const float4*)(w1p + cc * 4);
        #pragma unroll
        for (int i = 0; i < DPOS; ++i) {
            const float4 xv = *(const float4*)(xrow + i * CIN + cc * 4);
            acc0[i] += xv.x * w0.x + xv.y * w0.y + xv.z * w0.z + xv.w * w0.w;
            acc1[i] += xv.x * w1.x + xv.y * w1.y + xv.z * w1.z + xv.w * w1.w;
        }
    }

    // ---- combine: d[i], T held in 9 statically-indexed regs
    float d[DPOS], T = 0.f;
    #pragma unroll
    for (int i = 0; i < DPOS; ++i) { d[i] = acc0[i] - acc1[i]; T += acc1[i]; }

    float* outp = out + ((size_t)(block_s + s_local) * NPERM) * COUT + o;
    #pragma unroll 2
    for (int r = 0; r < NPERM; ++r) {
        const int m = masks[r];        // wave-uniform -> LDS broadcast
        float v = T;
        #pragma unroll
        for (int i = 0; i < DPOS; ++i)
            v += (m & (1 << i)) ? d[i] : 0.0f;   // v_cndmask + v_add, static d[i]
        outp[(size_t)r * COUT] = v;    // coalesced: 2x128B segments per wave store
    }
}

extern "C" void kernel_launch(void* const* d_in, const int* in_sizes, int n_in,
                              void* d_out, int out_size, void* d_ws, size_t ws_size,
                              hipStream_t stream) {
    const float* x  = (const float*)d_in[0];
    const float* w  = (const float*)d_in[1];
    const int*   s0 = (const int*)d_in[2];
    float* outp     = (float*)d_out;
    hipLaunchKernelGGL(pcs_kernel, dim3(NSAMP / SPB), dim3(256), 0, stream,
                       x, w, s0, outp);
}

// Round 2
// 108.598 us; speedup vs baseline: 1.0130x; 1.0130x over previous
//
#include <hip/hip_runtime.h>

#define NSAMP 8192
#define DPOS  8
#define CIN   64
#define COUT  32
#define NPERM 70

// out[s,r,o] = T[s,o] + sum_{i in splits0[r]} d[s,i,o]
//   p[i][g]  = dot(x[s,i,:], w[g,o,:]);  d = p0 - p1;  T = sum_i p1[i]
//
// Wave = 1 sample, lane = g*32+o. x row is wave-uniform -> SMEM/s_load path;
// w row lives in 64 VGPRs per lane. No LDS, no barrier. Masks are re-derived
// at compile time (sorted(set(permutations([0]*4+[1]*4))) == ascending 8-bit
// popcount-4 codes, MSB = position 0), so the combine loop folds to adds.

struct MaskTable { int m[NPERM]; };
static constexpr MaskTable build_masks() {
    MaskTable t{}; int idx = 0;
    for (int N = 0; N < 256; ++N) {
        int pc = 0;
        for (int b = 0; b < 8; ++b) pc += (N >> b) & 1;
        if (pc != 4) continue;
        int m = 0;
        for (int i = 0; i < 8; ++i)
            if (!((N >> (7 - i)) & 1)) m |= 1 << i;   // label==0 at position i
        t.m[idx++] = m;
    }
    return t;
}
static constexpr MaskTable MT = build_masks();

extern "C" __global__ __launch_bounds__(256, 4)
void pcs_kernel(const float* __restrict__ x,
                const float* __restrict__ w,
                float*       __restrict__ out)
{
    const int lane = threadIdx.x & 63;
    const int go   = lane;              // g*32 + o
    const int o    = lane & 31;
    const bool ghi = lane >= 32;        // g == 1

    // wave-uniform sample index (readfirstlane pins it to an SGPR)
    const int wave = __builtin_amdgcn_readfirstlane((int)(threadIdx.x >> 6));
    const int s    = blockIdx.x * 4 + wave;

    // ---- w row -> 64 VGPRs (16 KB total, L2-hot after first waves)
    float4 wv[16];
    const float* wrow = w + (size_t)go * CIN;
    #pragma unroll
    for (int c4 = 0; c4 < 16; ++c4)
        wv[c4] = *(const float4*)(wrow + c4 * 4);

    // ---- projection: acc[i] = dot(x[s,i,:], w[g,o,:]); x is wave-uniform
    const float* xrow = x + (size_t)s * (DPOS * CIN);
    float acc[DPOS];
    #pragma unroll
    for (int i = 0; i < DPOS; ++i) {
        float a0 = 0.f, a1 = 0.f, a2 = 0.f, a3 = 0.f;
        #pragma unroll
        for (int c4 = 0; c4 < 16; ++c4) {
            const float4 xv = *(const float4*)(xrow + i * CIN + c4 * 4);
            const float4 wq = wv[c4];
            a0 += xv.x * wq.x; a1 += xv.y * wq.y;
            a2 += xv.z * wq.z; a3 += xv.w * wq.w;
        }
        acc[i] = (a0 + a1) + (a2 + a3);
    }

    // ---- d[i] = p0-p1, T = sum p1 via half-wave exchange
    float d[DPOS], T = 0.f;
    #pragma unroll
    for (int i = 0; i < DPOS; ++i) {
        const float other = __shfl_xor(acc[i], 32);
        const float p0 = ghi ? other  : acc[i];
        const float p1 = ghi ? acc[i] : other;
        d[i] = p0 - p1;
        T += p1;
    }

    // ---- combine + store: lower half-wave handles r=k, upper r=k+35.
    // Masks are compile-time -> pure add chains, one cndmask + store per pair.
    float* outp = out + (size_t)s * (NPERM * COUT) + (ghi ? 35 * COUT : 0) + o;
    #pragma unroll
    for (int k = 0; k < 35; ++k) {
        float a = T, b = T;
        #pragma unroll
        for (int i = 0; i < DPOS; ++i) {
            if (MT.m[k]      & (1 << i)) a += d[i];
            if (MT.m[k + 35] & (1 << i)) b += d[i];
        }
        outp[k * COUT] = ghi ? b : a;   // two 128B segments per wave store
    }
}

extern "C" void kernel_launch(void* const* d_in, const int* in_sizes, int n_in,
                              void* d_out, int out_size, void* d_ws, size_t ws_size,
                              hipStream_t stream) {
    const float* x = (const float*)d_in[0];
    const float* w = (const float*)d_in[1];
    float* outp    = (float*)d_out;
    hipLaunchKernelGGL(pcs_kernel, dim3(NSAMP / 4), dim3(256), 0, stream,
                       x, w, outp);
}